// Round 10
// baseline (444.890 us; speedup 1.0000x reference)
//
#include <hip/hip_runtime.h>

typedef __attribute__((ext_vector_type(8))) short bf16x8;
typedef __attribute__((ext_vector_type(4))) float f32x4;

#define LOG2E 1.4426950408889634f
// full bank swizzle: XOR row bits (addr>>7) into 16B-chunk-select bits [4:6].
// Involution (bits >=7 untouched); permutes 16B chunks -> gload_lds-compatible.
#define SWZ(L) ((L) ^ ((((L) >> 7) & 7) << 4))

__device__ __forceinline__ unsigned short f2bf(float f) {
  unsigned int x = __builtin_bit_cast(unsigned int, f);
  x += 0x7fffu + ((x >> 16) & 1u);   // RNE
  return (unsigned short)(x >> 16);
}
__device__ __forceinline__ float bf2f(unsigned short u) {
  unsigned int x = ((unsigned int)u) << 16;
  return __builtin_bit_cast(float, x);
}

__device__ __forceinline__ void gload16(const void* g, void* l) {
  __builtin_amdgcn_global_load_lds((const __attribute__((address_space(1))) void*)g,
                                   (__attribute__((address_space(3))) void*)l, 16, 0, 0);
}

// swizzled ds_read of one bf16x8 fragment from a [128][64]-bf16 half-tile region
__device__ __forceinline__ bf16x8 ldsf(const char* region, int row, int colbyte) {
  const int L = row * 128 + colbyte;
  return *(const bf16x8*)(region + SWZ(L));
}

// stage one 128x64 bf16 half-tile (16 KB): linear LDS dest, inverse-swizzled source.
__device__ __forceinline__ void stage_half(const unsigned short* __restrict__ G, int rowbase,
                                           int K, int ku, char* region, int w, int l) {
#pragma unroll
  for (int i = 0; i < 2; ++i) {
    const int off = w * 1024 + i * 8192;
    const int P = off + l * 16;
    const int L = SWZ(P);
    const int r = L >> 7, cs = (L & 127) >> 1;
    gload16(G + (long long)(rowbase + r) * K + ku + cs, region + off);
  }
}

// ---------------------------------------------------------------- cast + pack
__global__ __launch_bounds__(256)
void cast_pack(const float* __restrict__ x, const float* __restrict__ wq,
               const float* __restrict__ wk, const float* __restrict__ wv,
               const float* __restrict__ wo,
               unsigned short* __restrict__ xb, unsigned short* __restrict__ wqkv,
               unsigned short* __restrict__ wob) {
  const int NX = 8388608, DD = 4194304;
  const int i = (blockIdx.x * 256 + threadIdx.x) * 4;
  const float* src; unsigned short* dst; float scale = 1.0f;
  if (i < NX)               { src = x + i;                    dst = xb + i; }
  else if (i < NX + DD)     { int o = i - NX;      src = wq + o; dst = wqkv + o; scale = 0.088388347648318447f; }
  else if (i < NX + 2*DD)   { int o = i - NX - DD;   src = wk + o; dst = wqkv + DD + o; }
  else if (i < NX + 3*DD)   { int o = i - NX - 2*DD; src = wv + o; dst = wqkv + 2*DD + o; }
  else                      { int o = i - NX - 3*DD; src = wo + o; dst = wob + o; }
  const float4 v = *(const float4*)src;
  ushort4 u;
  u.x = f2bf(v.x * scale); u.y = f2bf(v.y * scale);
  u.z = f2bf(v.z * scale); u.w = f2bf(v.w * scale);
  *(ushort4*)dst = u;
}

// ---------------------------------------------------------------- 128x256 GEMM  C = A @ B^T
// 512 thr = 8 waves (2M x 4N), BK=64, per-wave 64x64 (acc[4][4]).
// A: global->register staged (8 bf16x8 frags/wave/K-tile, reg double-buffered,
//    loop unrolled x2 for static indexing). LDS carries B only (64 KiB dbuf).
// Per K-tile: P0 = {8 B ds_reads + issue 8 A-reg loads for t+1} -> lgkm(0) ->
// 8 MFMA -> barrier (B reads drained, buffer d free) -> stage B[t+2] (4 DMA)
// -> 24 MFMA -> vmcnt(4) -> barrier.
// vmcnt(4) ordering: outstanding at tile end = A[t+1](8)+B[t+2](4)=12; waiting
// to 4 completes A[t+1] (needed next P0) and everything older incl. B[t+1].
// XCD map (R5-measured best): wg=(orig&7)*cpx+orig/8; bm=wg&31, bn=wg>>5.
// MODE 0: epilogue fuses RoPE for Q/K; V written transposed. MODE 1: f32 -> Of.
template<int MODE>
__global__ __launch_bounds__(512, 2)
void gemm256(const unsigned short* __restrict__ A, const unsigned short* __restrict__ Bw,
             float* __restrict__ Of, unsigned short* __restrict__ Qb,
             unsigned short* __restrict__ Kb, unsigned short* __restrict__ Vt,
             const float* __restrict__ fc, const float* __restrict__ fs, int K) {
  __shared__ char lds[65536];
  char* const Bbase = lds;            // + d*32768 + half*16384
  const int tid = threadIdx.x;
  const int l = tid & 63, w = tid >> 6;
  const int wr = w >> 2, wc = w & 3;
  const int lq = l & 15, g = l >> 4;
  const int nwg = gridDim.x;
  const int cpx = nwg >> 3;
  const int orig = blockIdx.x;
  const int wg = (orig & 7) * cpx + (orig >> 3);
  const int bm = wg & 31, bn = wg >> 5;        // M = 4096 -> 32 M-tiles of 128
  const unsigned short* Ab = A + (long long)bm * 128 * K;
  const unsigned short* Bb = Bw + (long long)bn * 256 * K;
  const int NT = K >> 6;
  const int brow0 = (wc & 1) * 64;
  const int arow0 = wr * 64;
  // per-lane A base: row (arow0+lq), col g*8; frag(mi,kk) at +mi*16*K + ku + kk*32
  const unsigned short* Alane = Ab + (long long)(arow0 + lq) * K + g * 8;

  bf16x8 aA[4][2], aB[4][2];
  // prologue: A[0]->regs (8 loads, oldest), then B[0],B[1] stages (8 DMA).
#pragma unroll
  for (int mi = 0; mi < 4; ++mi)
#pragma unroll
    for (int kk = 0; kk < 2; ++kk)
      aA[mi][kk] = *(const bf16x8*)(Alane + (long long)mi * 16 * K + kk * 32);
  stage_half(Bb, 0,   K, 0,  Bbase,         w, l);
  stage_half(Bb, 128, K, 0,  Bbase + 16384, w, l);
  stage_half(Bb, 0,   K, 64, Bbase + 32768, w, l);
  stage_half(Bb, 128, K, 64, Bbase + 49152, w, l);
  // wait: aA(8 oldest) + B[0](next 4) done; B[1](4) stays in flight
  asm volatile("s_waitcnt vmcnt(4)" ::: "memory");
  __builtin_amdgcn_s_barrier();

  f32x4 acc[4][4] = {};

#define GEMM_TILE(T, ACUR, ANXT)                                                                       \
  {                                                                                                    \
    const int d_ = (T) & 1;                                                                            \
    const char* Br = Bbase + d_ * 32768 + (wc >> 1) * 16384;                                           \
    bf16x8 b[2][4];                                                                                    \
    _Pragma("unroll") for (int kk = 0; kk < 2; ++kk)                                                   \
      _Pragma("unroll") for (int ni = 0; ni < 4; ++ni)                                                 \
        b[kk][ni] = ldsf(Br, brow0 + ni * 16 + lq, kk * 64 + g * 16);                                  \
    { const int u_ = (T) + 1; const long long ku_ = (u_ < NT) ? (long long)u_ * 64 : 0;                \
      _Pragma("unroll") for (int mi = 0; mi < 4; ++mi)                                                 \
        _Pragma("unroll") for (int kk = 0; kk < 2; ++kk)                                               \
          ANXT[mi][kk] = *(const bf16x8*)(Alane + (long long)mi * 16 * K + ku_ + kk * 32); }           \
    asm volatile("s_waitcnt lgkmcnt(0)" ::: "memory");                                                 \
    __builtin_amdgcn_sched_barrier(0);                                                                 \
    __builtin_amdgcn_s_setprio(1);                                                                     \
    _Pragma("unroll") for (int ni = 0; ni < 4; ++ni) {                                                 \
      acc[0][ni] = __builtin_amdgcn_mfma_f32_16x16x32_bf16(ACUR[0][0], b[0][ni], acc[0][ni], 0, 0, 0); \
      acc[1][ni] = __builtin_amdgcn_mfma_f32_16x16x32_bf16(ACUR[1][0], b[0][ni], acc[1][ni], 0, 0, 0); \
    }                                                                                                  \
    __builtin_amdgcn_s_setprio(0);                                                                     \
    __builtin_amdgcn_s_barrier();                                                                      \
    { const int u_ = (T) + 2; const int ku_ = (u_ < NT) ? u_ * 64 : 0;                                 \
      stage_half(Bb, 0,   K, ku_, Bbase + d_ * 32768, w, l);                                           \
      stage_half(Bb, 128, K, ku_, Bbase + d_ * 32768 + 16384, w, l); }                                 \
    __builtin_amdgcn_s_setprio(1);                                                                     \
    _Pragma("unroll") for (int ni = 0; ni < 4; ++ni) {                                                 \
      acc[2][ni] = __builtin_amdgcn_mfma_f32_16x16x32_bf16(ACUR[2][0], b[0][ni], acc[2][ni], 0, 0, 0); \
      acc[3][ni] = __builtin_amdgcn_mfma_f32_16x16x32_bf16(ACUR[3][0], b[0][ni], acc[3][ni], 0, 0, 0); \
    }                                                                                                  \
    _Pragma("unroll") for (int ni = 0; ni < 4; ++ni) {                                                 \
      acc[0][ni] = __builtin_amdgcn_mfma_f32_16x16x32_bf16(ACUR[0][1], b[1][ni], acc[0][ni], 0, 0, 0); \
      acc[1][ni] = __builtin_amdgcn_mfma_f32_16x16x32_bf16(ACUR[1][1], b[1][ni], acc[1][ni], 0, 0, 0); \
      acc[2][ni] = __builtin_amdgcn_mfma_f32_16x16x32_bf16(ACUR[2][1], b[1][ni], acc[2][ni], 0, 0, 0); \
      acc[3][ni] = __builtin_amdgcn_mfma_f32_16x16x32_bf16(ACUR[3][1], b[1][ni], acc[3][ni], 0, 0, 0); \
    }                                                                                                  \
    __builtin_amdgcn_s_setprio(0);                                                                     \
    asm volatile("s_waitcnt vmcnt(4)" ::: "memory");                                                   \
    __builtin_amdgcn_s_barrier();                                                                      \
  }

  for (int t = 0; t < NT; t += 2) {
    GEMM_TILE(t, aA, aB);
    GEMM_TILE(t + 1, aB, aA);
  }
#undef GEMM_TILE
  asm volatile("s_waitcnt vmcnt(0)" ::: "memory");   // drain DMA before exit

  // D layout per fragment: col = lq, row = g*4 + r
  if (MODE == 0) {
    const int colb = bn * 256;
    if (colb < 4096) {
      // Q or K with fused RoPE: pair (2j,2j+1) = adjacent lanes (lq, lq^1)
      unsigned short* dst = (colb < 2048) ? Qb : Kb;
      const int cb = colb & 2047;
#pragma unroll
      for (int mi = 0; mi < 4; ++mi) {
        const int row = bm * 128 + wr * 64 + mi * 16 + g * 4;
        const int s0 = row & 2047;
#pragma unroll
        for (int ni = 0; ni < 4; ++ni) {
          const int col = cb + wc * 64 + ni * 16 + lq;
          const int hd = col & 127;
          const int j = hd >> 1;
          const bool odd = hd & 1;
#pragma unroll
          for (int r = 0; r < 4; ++r) {
            const int s = s0 + r;
            const float c  = fc[s * 64 + j];
            const float sn = fs[s * 64 + j];
            const float own = acc[mi][ni][r];
            const float oth = __shfl_xor(own, 1);
            const float val = odd ? (oth * sn + own * c) : (own * c - oth * sn);
            dst[(long long)(row + r) * 2048 + col] = f2bf(val);
          }
        }
      }
    } else {
#pragma unroll
      for (int mi = 0; mi < 4; ++mi) {
        const int row = bm * 128 + wr * 64 + mi * 16 + g * 4;   // b*2048 + s
        const int b = row >> 11, s = row & 2047;
#pragma unroll
        for (int ni = 0; ni < 4; ++ni) {
          const int c = colb - 4096 + wc * 64 + ni * 16 + lq;    // h*128 + d
          const int h = c >> 7, dd = c & 127;
          ushort4 o4;
          o4.x = f2bf(acc[mi][ni][0]); o4.y = f2bf(acc[mi][ni][1]);
          o4.z = f2bf(acc[mi][ni][2]); o4.w = f2bf(acc[mi][ni][3]);
          *(ushort4*)&Vt[((long long)((b * 16 + h) * 128 + dd)) * 2048 + s] = o4;
        }
      }
    }
  } else {
#pragma unroll
    for (int mi = 0; mi < 4; ++mi) {
      const int row = bm * 128 + wr * 64 + mi * 16 + g * 4;
#pragma unroll
      for (int ni = 0; ni < 4; ++ni) {
        const int col = bn * 256 + wc * 64 + ni * 16 + lq;
#pragma unroll
        for (int r = 0; r < 4; ++r)
          Of[(long long)(row + r) * 2048 + col] = acc[mi][ni][r];
      }
    }
  }
}

// ---------------------------------------------------------------- sliding-window attention
// (unchanged from R9)
__global__ __launch_bounds__(256)
void attn_k(const unsigned short* __restrict__ Qb, const unsigned short* __restrict__ Kb,
            const unsigned short* __restrict__ Vt, unsigned short* __restrict__ Ob) {
  __shared__ unsigned short plds[8192];   // 4 waves x 4 KB (2 tiles x 2 KB)
  const int tid = threadIdx.x;
  const int l = tid & 63, w = tid >> 6;
  const int lq = l & 15, g = l >> 4;
  const int qb = blockIdx.x, bh = blockIdx.y;
  const int b = bh >> 4, h = bh & 15;
  const int q_abs = qb * 64 + w * 16 + lq;
  const unsigned short* Qrow = Qb + ((long long)(b * 2048 + q_abs)) * 2048 + h * 128;
  bf16x8 qf[4];
#pragma unroll
  for (int ks = 0; ks < 4; ++ks)
    qf[ks] = *(const bf16x8*)&Qrow[ks * 32 + g * 8];
  f32x4 o[8] = {};
  float m = -1e30f, lsum = 0.0f;
  char* pb = (char*)(plds + w * 2048);
  const unsigned short* Kbase = Kb + ((long long)(b * 2048)) * 2048 + h * 128;
  const unsigned short* Vbase = Vt + ((long long)bh) * 128 * 2048;
  const int kb_lo = (qb >= 4) ? qb - 4 : 0;
  for (int kb = kb_lo; kb <= qb; kb += 2) {
    const bool hb = (kb + 1 <= qb);          // block-uniform
    const int key0 = kb * 64;
    float sva[16], svb[16];
    {
      f32x4 sc[4] = {};
      __builtin_amdgcn_s_setprio(1);
#pragma unroll
      for (int mt = 0; mt < 4; ++mt) {
        const unsigned short* Krow = Kbase + (long long)(key0 + mt * 16 + lq) * 2048;
#pragma unroll
        for (int ks = 0; ks < 4; ++ks) {
          const bf16x8 kf = *(const bf16x8*)&Krow[ks * 32 + g * 8];
          sc[mt] = __builtin_amdgcn_mfma_f32_16x16x32_bf16(kf, qf[ks], sc[mt], 0, 0, 0);
        }
      }
      __builtin_amdgcn_s_setprio(0);
#pragma unroll
      for (int mt = 0; mt < 4; ++mt)
#pragma unroll
        for (int r = 0; r < 4; ++r) {
          const int key = key0 + mt * 16 + g * 4 + r;
          const bool valid = (key <= q_abs) && (key + 256 > q_abs);
          sva[mt * 4 + r] = valid ? sc[mt][r] : -1e30f;
        }
    }
    if (hb) {
      f32x4 sc[4] = {};
      __builtin_amdgcn_s_setprio(1);
#pragma unroll
      for (int mt = 0; mt < 4; ++mt) {
        const unsigned short* Krow = Kbase + (long long)(key0 + 64 + mt * 16 + lq) * 2048;
#pragma unroll
        for (int ks = 0; ks < 4; ++ks) {
          const bf16x8 kf = *(const bf16x8*)&Krow[ks * 32 + g * 8];
          sc[mt] = __builtin_amdgcn_mfma_f32_16x16x32_bf16(kf, qf[ks], sc[mt], 0, 0, 0);
        }
      }
      __builtin_amdgcn_s_setprio(0);
#pragma unroll
      for (int mt = 0; mt < 4; ++mt)
#pragma unroll
        for (int r = 0; r < 4; ++r) {
          const int key = key0 + 64 + mt * 16 + g * 4 + r;
          const bool valid = (key <= q_abs) && (key + 256 > q_abs);
          svb[mt * 4 + r] = valid ? sc[mt][r] : -1e30f;
        }
    } else {
#pragma unroll
      for (int i = 0; i < 16; ++i) svb[i] = -1e30f;
    }
    float bmax = -1e30f;
#pragma unroll
    for (int i = 0; i < 16; ++i) bmax = fmaxf(bmax, fmaxf(sva[i], svb[i]));
    bmax = fmaxf(bmax, __shfl_xor(bmax, 16));
    bmax = fmaxf(bmax, __shfl_xor(bmax, 32));
    const float mnew = fmaxf(m, bmax);
    float psum = 0.0f;
#pragma unroll
    for (int i = 0; i < 16; ++i) {
      const float p = __builtin_exp2f((sva[i] - mnew) * LOG2E);
      sva[i] = p; psum += p;
    }
#pragma unroll
    for (int i = 0; i < 16; ++i) {
      const float p = __builtin_exp2f((svb[i] - mnew) * LOG2E);
      svb[i] = p; psum += p;
    }
    psum += __shfl_xor(psum, 16);
    psum += __shfl_xor(psum, 32);
    if (mnew > m) {
      const float rf = __builtin_exp2f((m - mnew) * LOG2E);
      lsum = lsum * rf + psum;
      m = mnew;
#pragma unroll
      for (int dt = 0; dt < 8; ++dt) o[dt] *= rf;
    } else {
      lsum += psum;
    }
#pragma unroll
    for (int mt = 0; mt < 4; ++mt) {
      const unsigned int lo = (unsigned int)f2bf(sva[mt * 4 + 0]) | ((unsigned int)f2bf(sva[mt * 4 + 1]) << 16);
      const unsigned int hi = (unsigned int)f2bf(sva[mt * 4 + 2]) | ((unsigned int)f2bf(sva[mt * 4 + 3]) << 16);
      int byte = lq * 128 + (mt * 16 + g * 4) * 2;
      byte ^= (lq & 7) << 4;
      *(uint2*)(pb + byte) = make_uint2(lo, hi);
    }
    if (hb) {
#pragma unroll
      for (int mt = 0; mt < 4; ++mt) {
        const unsigned int lo = (unsigned int)f2bf(svb[mt * 4 + 0]) | ((unsigned int)f2bf(svb[mt * 4 + 1]) << 16);
        const unsigned int hi = (unsigned int)f2bf(svb[mt * 4 + 2]) | ((unsigned int)f2bf(svb[mt * 4 + 3]) << 16);
        int byte = lq * 128 + (mt * 16 + g * 4) * 2;
        byte ^= (lq & 7) << 4;
        *(uint2*)(pb + 2048 + byte) = make_uint2(lo, hi);
      }
    }
    asm volatile("s_waitcnt lgkmcnt(0)" ::: "memory");
    __builtin_amdgcn_sched_barrier(0);
    bf16x8 pfa[2], pfb[2];
#pragma unroll
    for (int k2 = 0; k2 < 2; ++k2) {
      int byte = lq * 128 + k2 * 64 + g * 16;
      byte ^= (lq & 7) << 4;
      pfa[k2] = *(const bf16x8*)(pb + byte);
      if (hb) pfb[k2] = *(const bf16x8*)(pb + 2048 + byte);
    }
    asm volatile("s_waitcnt lgkmcnt(0)" ::: "memory");
    __builtin_amdgcn_sched_barrier(0);
    __builtin_amdgcn_s_setprio(1);
#pragma unroll
    for (int dt = 0; dt < 8; ++dt) {
      const unsigned short* Vrow = Vbase + (long long)(dt * 16 + lq) * 2048 + key0;
#pragma unroll
      for (int k2 = 0; k2 < 2; ++k2) {
        const bf16x8 vf = *(const bf16x8*)&Vrow[k2 * 32 + g * 8];
        o[dt] = __builtin_amdgcn_mfma_f32_16x16x32_bf16(vf, pfa[k2], o[dt], 0, 0, 0);
      }
      if (hb) {
#pragma unroll
        for (int k2 = 0; k2 < 2; ++k2) {
          const bf16x8 vf = *(const bf16x8*)&Vrow[64 + k2 * 32 + g * 8];
          o[dt] = __builtin_amdgcn_mfma_f32_16x16x32_bf16(vf, pfb[k2], o[dt], 0, 0, 0);
        }
      }
    }
    __builtin_amdgcn_s_setprio(0);
  }
  const float inv = 1.0f / lsum;
  unsigned short* Or = Ob + ((long long)(b * 2048 + q_abs)) * 2048 + h * 128;
#pragma unroll
  for (int dt = 0; dt < 8; ++dt) {
    ushort4 o4;
    o4.x = f2bf(o[dt][0] * inv);
    o4.y = f2bf(o[dt][1] * inv);
    o4.z = f2bf(o[dt][2] * inv);
    o4.w = f2bf(o[dt][3] * inv);
    *(ushort4*)&Or[dt * 16 + g * 4] = o4;
  }
}

// ----------------------------------------------------------------
extern "C" void kernel_launch(void* const* d_in, const int* in_sizes, int n_in,
                              void* d_out, int out_size, void* d_ws, size_t ws_size,
                              hipStream_t stream) {
  const float* x  = (const float*)d_in[0];
  const float* fc = (const float*)d_in[1];
  const float* fs = (const float*)d_in[2];
  const float* wq = (const float*)d_in[3];
  const float* wk = (const float*)d_in[4];
  const float* wv = (const float*)d_in[5];
  const float* wo = (const float*)d_in[6];

  unsigned short* ws   = (unsigned short*)d_ws;
  unsigned short* xb   = ws;                       //  8388608
  unsigned short* wqkv = xb + 8388608;             // 12582912
  unsigned short* wob  = wqkv + 12582912;          //  4194304
  unsigned short* Qb   = wob + 4194304;            //  8388608
  unsigned short* Kb   = Qb + 8388608;             //  8388608
  unsigned short* Vt   = Kb + 8388608;             //  8388608  [b,h,d,s]
  unsigned short* Ob   = Vt + 8388608;             //  8388608

  cast_pack<<<24576, 256, 0, stream>>>(x, wq, wk, wv, wo, xb, wqkv, wob);
  gemm256<0><<<768, 512, 0, stream>>>(xb, wqkv, nullptr, Qb, Kb, Vt, fc, fs, 2048);
  attn_k<<<dim3(32, 32), 256, 0, stream>>>(Qb, Kb, Vt, Ob);
  gemm256<1><<<256, 512, 0, stream>>>(Ob, wob, (float*)d_out, nullptr, nullptr, nullptr, fc, fs, 2048);
}

// Round 11
// 211.215 us; speedup vs baseline: 2.1063x; 2.1063x over previous
//
#include <hip/hip_runtime.h>

typedef __attribute__((ext_vector_type(8))) short bf16x8;
typedef __attribute__((ext_vector_type(4))) float f32x4;

#define LOG2E 1.4426950408889634f
// full bank swizzle: XOR row bits (addr>>7) into 16B-chunk-select bits [4:6].
// Involution (bits >=7 untouched); permutes 16B chunks -> gload_lds-compatible.
#define SWZ(L) ((L) ^ ((((L) >> 7) & 7) << 4))
// K-tile variant for 256B rows: XOR row bits (addr>>8) into chunk bits [4:6].
#define SWZK(L) ((L) ^ ((((L) >> 8) & 7) << 4))

__device__ __forceinline__ unsigned short f2bf(float f) {
  unsigned int x = __builtin_bit_cast(unsigned int, f);
  x += 0x7fffu + ((x >> 16) & 1u);   // RNE
  return (unsigned short)(x >> 16);
}
__device__ __forceinline__ float bf2f(unsigned short u) {
  unsigned int x = ((unsigned int)u) << 16;
  return __builtin_bit_cast(float, x);
}

__device__ __forceinline__ void gload16(const void* g, void* l) {
  __builtin_amdgcn_global_load_lds((const __attribute__((address_space(1))) void*)g,
                                   (__attribute__((address_space(3))) void*)l, 16, 0, 0);
}

// swizzled ds_read of one bf16x8 fragment from a [128][64]-bf16 (128B-row) region
__device__ __forceinline__ bf16x8 ldsf(const char* region, int row, int colbyte) {
  const int L = row * 128 + colbyte;
  return *(const bf16x8*)(region + SWZ(L));
}
// swizzled ds_read from a [64][128]-bf16 (256B-row) K region
__device__ __forceinline__ bf16x8 ldsfK(const char* region, int row, int colbyte) {
  const int L = row * 256 + colbyte;
  return *(const bf16x8*)(region + SWZK(L));
}

// stage one 128x64 bf16 half-tile (16 KB): linear LDS dest, inverse-swizzled source.
__device__ __forceinline__ void stage_half(const unsigned short* __restrict__ G, int rowbase,
                                           int K, int ku, char* region, int w, int l) {
#pragma unroll
  for (int i = 0; i < 2; ++i) {
    const int off = w * 1024 + i * 8192;
    const int P = off + l * 16;
    const int L = SWZ(P);
    const int r = L >> 7, cs = (L & 127) >> 1;
    gload16(G + (long long)(rowbase + r) * K + ku + cs, region + off);
  }
}

// ---------------------------------------------------------------- cast + pack
__global__ __launch_bounds__(256)
void cast_pack(const float* __restrict__ x, const float* __restrict__ wq,
               const float* __restrict__ wk, const float* __restrict__ wv,
               const float* __restrict__ wo,
               unsigned short* __restrict__ xb, unsigned short* __restrict__ wqkv,
               unsigned short* __restrict__ wob) {
  const int NX = 8388608, DD = 4194304;
  const int i = (blockIdx.x * 256 + threadIdx.x) * 4;
  const float* src; unsigned short* dst; float scale = 1.0f;
  if (i < NX)               { src = x + i;                    dst = xb + i; }
  else if (i < NX + DD)     { int o = i - NX;      src = wq + o; dst = wqkv + o; scale = 0.088388347648318447f; }
  else if (i < NX + 2*DD)   { int o = i - NX - DD;   src = wk + o; dst = wqkv + DD + o; }
  else if (i < NX + 3*DD)   { int o = i - NX - 2*DD; src = wv + o; dst = wqkv + 2*DD + o; }
  else                      { int o = i - NX - 3*DD; src = wo + o; dst = wob + o; }
  const float4 v = *(const float4*)src;
  ushort4 u;
  u.x = f2bf(v.x * scale); u.y = f2bf(v.y * scale);
  u.z = f2bf(v.z * scale); u.w = f2bf(v.w * scale);
  *(ushort4*)dst = u;
}

// ---------------------------------------------------------------- 128x256 GEMM  C = A @ B^T
// (R8 kernel verbatim — measured 121 us QKV, MfmaUtil 36.6%, conflicts 0)
template<int MODE>
__global__ __launch_bounds__(512, 2)
void gemm256(const unsigned short* __restrict__ A, const unsigned short* __restrict__ Bw,
             float* __restrict__ Of, unsigned short* __restrict__ Qb,
             unsigned short* __restrict__ Kb, unsigned short* __restrict__ Vt,
             const float* __restrict__ fc, const float* __restrict__ fs, int K) {
  __shared__ char lds[98304];
  char* const Abase = lds;            // + d*16384
  char* const Bbase = lds + 32768;    // + d*32768 + half*16384
  const int tid = threadIdx.x;
  const int l = tid & 63, w = tid >> 6;
  const int wr = w >> 2, wc = w & 3;
  const int lq = l & 15, g = l >> 4;
  const int nwg = gridDim.x;
  const int cpx = nwg >> 3;
  const int orig = blockIdx.x;
  const int wg = (orig & 7) * cpx + (orig >> 3);
  const int bm = wg & 31, bn = wg >> 5;        // M = 4096 -> 32 M-tiles of 128
  const unsigned short* Ab = A + (long long)bm * 128 * K;
  const unsigned short* Bb = Bw + (long long)bn * 256 * K;
  const int NT = K >> 6;

  stage_half(Bb, 0,   K, 0,  Bbase,         w, l);
  stage_half(Bb, 128, K, 0,  Bbase + 16384, w, l);
  stage_half(Ab, 0,   K, 0,  Abase,         w, l);
  stage_half(Bb, 0,   K, 64, Bbase + 32768, w, l);
  stage_half(Bb, 128, K, 64, Bbase + 49152, w, l);
  asm volatile("s_waitcnt vmcnt(4)" ::: "memory");
  __builtin_amdgcn_s_barrier();

  f32x4 acc[4][4] = {};
  const int brow0 = (wc & 1) * 64;
  const int arow0 = wr * 64;
  for (int t = 0; t < NT; ++t) {
    const int d = t & 1;
    const char* Ar = Abase + d * 16384;
    const char* Br = Bbase + d * 32768 + (wc >> 1) * 16384;
    bf16x8 a0, a1, b[2][4];
    // ---- P0
#pragma unroll
    for (int kk = 0; kk < 2; ++kk)
#pragma unroll
      for (int ni = 0; ni < 4; ++ni)
        b[kk][ni] = ldsf(Br, brow0 + ni * 16 + lq, kk * 64 + g * 16);
    a0 = ldsf(Ar, arow0 + 0 * 16 + lq, g * 16);
    a1 = ldsf(Ar, arow0 + 1 * 16 + lq, g * 16);
    { const int u = t + 1; const int ku = (u < NT) ? u * 64 : 0;
      stage_half(Ab, 0, K, ku, Abase + (u & 1) * 16384, w, l); }
    asm volatile("s_waitcnt lgkmcnt(0)" ::: "memory");
    __builtin_amdgcn_sched_barrier(0);
    __builtin_amdgcn_s_setprio(1);
#pragma unroll
    for (int ni = 0; ni < 4; ++ni) {
      acc[0][ni] = __builtin_amdgcn_mfma_f32_16x16x32_bf16(a0, b[0][ni], acc[0][ni], 0, 0, 0);
      acc[1][ni] = __builtin_amdgcn_mfma_f32_16x16x32_bf16(a1, b[0][ni], acc[1][ni], 0, 0, 0);
    }
    __builtin_amdgcn_s_setprio(0);
    __builtin_amdgcn_s_barrier();
    // ---- P1
    a0 = ldsf(Ar, arow0 + 2 * 16 + lq, g * 16);
    a1 = ldsf(Ar, arow0 + 3 * 16 + lq, g * 16);
    { const int u = t + 2; const int ku = (u < NT) ? u * 64 : 0;
      stage_half(Bb, 0, K, ku, Bbase + d * 32768, w, l); }
    asm volatile("s_waitcnt lgkmcnt(0)" ::: "memory");
    __builtin_amdgcn_sched_barrier(0);
    __builtin_amdgcn_s_setprio(1);
#pragma unroll
    for (int ni = 0; ni < 4; ++ni) {
      acc[2][ni] = __builtin_amdgcn_mfma_f32_16x16x32_bf16(a0, b[0][ni], acc[2][ni], 0, 0, 0);
      acc[3][ni] = __builtin_amdgcn_mfma_f32_16x16x32_bf16(a1, b[0][ni], acc[3][ni], 0, 0, 0);
    }
    __builtin_amdgcn_s_setprio(0);
    __builtin_amdgcn_s_barrier();
    // ---- P2
    a0 = ldsf(Ar, arow0 + 0 * 16 + lq, 64 + g * 16);
    a1 = ldsf(Ar, arow0 + 1 * 16 + lq, 64 + g * 16);
    { const int u = t + 2; const int ku = (u < NT) ? u * 64 : 0;
      stage_half(Bb, 128, K, ku, Bbase + d * 32768 + 16384, w, l); }
    asm volatile("s_waitcnt lgkmcnt(0)" ::: "memory");
    __builtin_amdgcn_sched_barrier(0);
    __builtin_amdgcn_s_setprio(1);
#pragma unroll
    for (int ni = 0; ni < 4; ++ni) {
      acc[0][ni] = __builtin_amdgcn_mfma_f32_16x16x32_bf16(a0, b[1][ni], acc[0][ni], 0, 0, 0);
      acc[1][ni] = __builtin_amdgcn_mfma_f32_16x16x32_bf16(a1, b[1][ni], acc[1][ni], 0, 0, 0);
    }
    __builtin_amdgcn_s_setprio(0);
    __builtin_amdgcn_s_barrier();
    // ---- P3
    a0 = ldsf(Ar, arow0 + 2 * 16 + lq, 64 + g * 16);
    a1 = ldsf(Ar, arow0 + 3 * 16 + lq, 64 + g * 16);
    asm volatile("s_waitcnt lgkmcnt(0)" ::: "memory");
    __builtin_amdgcn_sched_barrier(0);
    __builtin_amdgcn_s_setprio(1);
#pragma unroll
    for (int ni = 0; ni < 4; ++ni) {
      acc[2][ni] = __builtin_amdgcn_mfma_f32_16x16x32_bf16(a0, b[1][ni], acc[2][ni], 0, 0, 0);
      acc[3][ni] = __builtin_amdgcn_mfma_f32_16x16x32_bf16(a1, b[1][ni], acc[3][ni], 0, 0, 0);
    }
    __builtin_amdgcn_s_setprio(0);
    asm volatile("s_waitcnt vmcnt(4)" ::: "memory");
    __builtin_amdgcn_s_barrier();
  }
  asm volatile("s_waitcnt vmcnt(0)" ::: "memory");   // drain DMA before exit

  if (MODE == 0) {
    const int colb = bn * 256;
    if (colb < 4096) {
      unsigned short* dst = (colb < 2048) ? Qb : Kb;
      const int cb = colb & 2047;
#pragma unroll
      for (int mi = 0; mi < 4; ++mi) {
        const int row = bm * 128 + wr * 64 + mi * 16 + g * 4;
        const int s0 = row & 2047;
#pragma unroll
        for (int ni = 0; ni < 4; ++ni) {
          const int col = cb + wc * 64 + ni * 16 + lq;
          const int hd = col & 127;
          const int j = hd >> 1;
          const bool odd = hd & 1;
#pragma unroll
          for (int r = 0; r < 4; ++r) {
            const int s = s0 + r;
            const float c  = fc[s * 64 + j];
            const float sn = fs[s * 64 + j];
            const float own = acc[mi][ni][r];
            const float oth = __shfl_xor(own, 1);
            const float val = odd ? (oth * sn + own * c) : (own * c - oth * sn);
            dst[(long long)(row + r) * 2048 + col] = f2bf(val);
          }
        }
      }
    } else {
#pragma unroll
      for (int mi = 0; mi < 4; ++mi) {
        const int row = bm * 128 + wr * 64 + mi * 16 + g * 4;   // b*2048 + s
        const int b = row >> 11, s = row & 2047;
#pragma unroll
        for (int ni = 0; ni < 4; ++ni) {
          const int c = colb - 4096 + wc * 64 + ni * 16 + lq;    // h*128 + d
          const int h = c >> 7, dd = c & 127;
          ushort4 o4;
          o4.x = f2bf(acc[mi][ni][0]); o4.y = f2bf(acc[mi][ni][1]);
          o4.z = f2bf(acc[mi][ni][2]); o4.w = f2bf(acc[mi][ni][3]);
          *(ushort4*)&Vt[((long long)((b * 16 + h) * 128 + dd)) * 2048 + s] = o4;
        }
      }
    }
  } else {
#pragma unroll
    for (int mi = 0; mi < 4; ++mi) {
      const int row = bm * 128 + wr * 64 + mi * 16 + g * 4;
#pragma unroll
      for (int ni = 0; ni < 4; ++ni) {
        const int col = bn * 256 + wc * 64 + ni * 16 + lq;
#pragma unroll
        for (int r = 0; r < 4; ++r)
          Of[(long long)(row + r) * 2048 + col] = acc[mi][ni][r];
      }
    }
  }
}

// ---------------------------------------------------------------- sliding-window attention
// LDS-staged K/V: all 4 waves share one (bh,qb) -> stage each 64-key K tile
// ([64][256B], SWZK) and V tile ([128][128B], SWZ) once per block instead of
// 4x per-wave VMEM streams. Two barriers/iter: loop-top (WAR: all reads of the
// previous tiles are lgkm-drained before each wave's MFMAs, so arrival implies
// done) and post-staging vmcnt(0). P round-trip stays wave-private.
__global__ __launch_bounds__(256)
void attn_k(const unsigned short* __restrict__ Qb, const unsigned short* __restrict__ Kb,
            const unsigned short* __restrict__ Vt, unsigned short* __restrict__ Ob) {
  __shared__ char kl[32768];               // 2 x [64 key][256 B]
  __shared__ char vl[32768];               // 2 x [128 d][128 B]
  __shared__ unsigned short plds[8192];    // 4 waves x 4 KB (2 tiles x 2 KB)
  const int tid = threadIdx.x;
  const int l = tid & 63, w = tid >> 6;
  const int lq = l & 15, g = l >> 4;
  const int qb = blockIdx.x, bh = blockIdx.y;
  const int b = bh >> 4, h = bh & 15;
  const int q_abs = qb * 64 + w * 16 + lq;
  const unsigned short* Qrow = Qb + ((long long)(b * 2048 + q_abs)) * 2048 + h * 128;
  bf16x8 qf[4];
#pragma unroll
  for (int ks = 0; ks < 4; ++ks)
    qf[ks] = *(const bf16x8*)&Qrow[ks * 32 + g * 8];
  f32x4 o[8] = {};
  float m = -1e30f, lsum = 0.0f;
  char* pb = (char*)(plds + w * 2048);
  const unsigned short* Kpanel = Kb + ((long long)(b * 2048)) * 2048 + h * 128;
  const unsigned short* Vbase = Vt + ((long long)bh) * 128 * 2048;
  const int kb_lo = (qb >= 4) ? qb - 4 : 0;
  for (int kb = kb_lo; kb <= qb; kb += 2) {
    const bool hb = (kb + 1 <= qb);          // block-uniform
    const int key0 = kb * 64;
    // ---- stage K/V tiles (cooperative, 4 waves)
    __builtin_amdgcn_s_barrier();            // prev-iter K/V reads complete
#pragma unroll
    for (int i = 0; i < 4; ++i) {            // K tile A
      const int off = i * 4096 + w * 1024;
      const int P = off + l * 16;
      const int L = SWZK(P);
      gload16(Kpanel + (long long)(key0 + (L >> 8)) * 2048 + ((L & 255) >> 1), kl + off);
    }
#pragma unroll
    for (int i = 0; i < 4; ++i) {            // V tile A
      const int off = i * 4096 + w * 1024;
      const int P = off + l * 16;
      const int L = SWZ(P);
      gload16(Vbase + (long long)(L >> 7) * 2048 + key0 + ((L & 127) >> 1), vl + off);
    }
    if (hb) {
#pragma unroll
      for (int i = 0; i < 4; ++i) {          // K tile B
        const int off = i * 4096 + w * 1024;
        const int P = off + l * 16;
        const int L = SWZK(P);
        gload16(Kpanel + (long long)(key0 + 64 + (L >> 8)) * 2048 + ((L & 255) >> 1), kl + 16384 + off);
      }
#pragma unroll
      for (int i = 0; i < 4; ++i) {          // V tile B
        const int off = i * 4096 + w * 1024;
        const int P = off + l * 16;
        const int L = SWZ(P);
        gload16(Vbase + (long long)(L >> 7) * 2048 + key0 + 64 + ((L & 127) >> 1), vl + 16384 + off);
      }
    }
    asm volatile("s_waitcnt vmcnt(0)" ::: "memory");
    __builtin_amdgcn_s_barrier();
    // ---- QK^T from LDS
    float sva[16], svb[16];
    {
      f32x4 sc[4] = {};
      __builtin_amdgcn_s_setprio(1);
#pragma unroll
      for (int mt = 0; mt < 4; ++mt)
#pragma unroll
        for (int ks = 0; ks < 4; ++ks) {
          const bf16x8 kf = ldsfK(kl, mt * 16 + lq, ks * 64 + g * 16);
          sc[mt] = __builtin_amdgcn_mfma_f32_16x16x32_bf16(kf, qf[ks], sc[mt], 0, 0, 0);
        }
      __builtin_amdgcn_s_setprio(0);
#pragma unroll
      for (int mt = 0; mt < 4; ++mt)
#pragma unroll
        for (int r = 0; r < 4; ++r) {
          const int key = key0 + mt * 16 + g * 4 + r;
          const bool valid = (key <= q_abs) && (key + 256 > q_abs);
          sva[mt * 4 + r] = valid ? sc[mt][r] : -1e30f;
        }
    }
    if (hb) {
      f32x4 sc[4] = {};
      __builtin_amdgcn_s_setprio(1);
#pragma unroll
      for (int mt = 0; mt < 4; ++mt)
#pragma unroll
        for (int ks = 0; ks < 4; ++ks) {
          const bf16x8 kf = ldsfK(kl + 16384, mt * 16 + lq, ks * 64 + g * 16);
          sc[mt] = __builtin_amdgcn_mfma_f32_16x16x32_bf16(kf, qf[ks], sc[mt], 0, 0, 0);
        }
      __builtin_amdgcn_s_setprio(0);
#pragma unroll
      for (int mt = 0; mt < 4; ++mt)
#pragma unroll
        for (int r = 0; r < 4; ++r) {
          const int key = key0 + 64 + mt * 16 + g * 4 + r;
          const bool valid = (key <= q_abs) && (key + 256 > q_abs);
          svb[mt * 4 + r] = valid ? sc[mt][r] : -1e30f;
        }
    } else {
#pragma unroll
      for (int i = 0; i < 16; ++i) svb[i] = -1e30f;
    }
    // ---- joint online softmax over 128 keys
    float bmax = -1e30f;
#pragma unroll
    for (int i = 0; i < 16; ++i) bmax = fmaxf(bmax, fmaxf(sva[i], svb[i]));
    bmax = fmaxf(bmax, __shfl_xor(bmax, 16));
    bmax = fmaxf(bmax, __shfl_xor(bmax, 32));
    const float mnew = fmaxf(m, bmax);
    float psum = 0.0f;
#pragma unroll
    for (int i = 0; i < 16; ++i) {
      const float p = __builtin_exp2f((sva[i] - mnew) * LOG2E);
      sva[i] = p; psum += p;
    }
#pragma unroll
    for (int i = 0; i < 16; ++i) {
      const float p = __builtin_exp2f((svb[i] - mnew) * LOG2E);
      svb[i] = p; psum += p;
    }
    psum += __shfl_xor(psum, 16);
    psum += __shfl_xor(psum, 32);
    if (mnew > m) {                      // wave-uniform rescale-skip
      const float rf = __builtin_exp2f((m - mnew) * LOG2E);
      lsum = lsum * rf + psum;
      m = mnew;
#pragma unroll
      for (int dt = 0; dt < 8; ++dt) o[dt] *= rf;
    } else {
      lsum += psum;
    }
    // ---- P -> LDS (wave-private), one round-trip
#pragma unroll
    for (int mt = 0; mt < 4; ++mt) {
      const unsigned int lo = (unsigned int)f2bf(sva[mt * 4 + 0]) | ((unsigned int)f2bf(sva[mt * 4 + 1]) << 16);
      const unsigned int hi = (unsigned int)f2bf(sva[mt * 4 + 2]) | ((unsigned int)f2bf(sva[mt * 4 + 3]) << 16);
      int byte = lq * 128 + (mt * 16 + g * 4) * 2;
      byte ^= (lq & 7) << 4;
      *(uint2*)(pb + byte) = make_uint2(lo, hi);
    }
    if (hb) {
#pragma unroll
      for (int mt = 0; mt < 4; ++mt) {
        const unsigned int lo = (unsigned int)f2bf(svb[mt * 4 + 0]) | ((unsigned int)f2bf(svb[mt * 4 + 1]) << 16);
        const unsigned int hi = (unsigned int)f2bf(svb[mt * 4 + 2]) | ((unsigned int)f2bf(svb[mt * 4 + 3]) << 16);
        int byte = lq * 128 + (mt * 16 + g * 4) * 2;
        byte ^= (lq & 7) << 4;
        *(uint2*)(pb + 2048 + byte) = make_uint2(lo, hi);
      }
    }
    asm volatile("s_waitcnt lgkmcnt(0)" ::: "memory");
    __builtin_amdgcn_sched_barrier(0);
    bf16x8 pfa[2], pfb[2];
#pragma unroll
    for (int k2 = 0; k2 < 2; ++k2) {
      int byte = lq * 128 + k2 * 64 + g * 16;
      byte ^= (lq & 7) << 4;
      pfa[k2] = *(const bf16x8*)(pb + byte);
      if (hb) pfb[k2] = *(const bf16x8*)(pb + 2048 + byte);
    }
    asm volatile("s_waitcnt lgkmcnt(0)" ::: "memory");
    __builtin_amdgcn_sched_barrier(0);
    // ---- PV from LDS V
    __builtin_amdgcn_s_setprio(1);
#pragma unroll
    for (int dt = 0; dt < 8; ++dt) {
#pragma unroll
      for (int k2 = 0; k2 < 2; ++k2) {
        const bf16x8 vf = ldsf(vl, dt * 16 + lq, k2 * 64 + g * 16);
        o[dt] = __builtin_amdgcn_mfma_f32_16x16x32_bf16(vf, pfa[k2], o[dt], 0, 0, 0);
      }
      if (hb) {
#pragma unroll
        for (int k2 = 0; k2 < 2; ++k2) {
          const bf16x8 vf = ldsf(vl + 16384, dt * 16 + lq, k2 * 64 + g * 16);
          o[dt] = __builtin_amdgcn_mfma_f32_16x16x32_bf16(vf, pfb[k2], o[dt], 0, 0, 0);
        }
      }
    }
    __builtin_amdgcn_s_setprio(0);
  }
  const float inv = 1.0f / lsum;
  unsigned short* Or = Ob + ((long long)(b * 2048 + q_abs)) * 2048 + h * 128;
#pragma unroll
  for (int dt = 0; dt < 8; ++dt) {
    ushort4 o4;
    o4.x = f2bf(o[dt][0] * inv);
    o4.y = f2bf(o[dt][1] * inv);
    o4.z = f2bf(o[dt][2] * inv);
    o4.w = f2bf(o[dt][3] * inv);
    *(ushort4*)&Or[dt * 16 + g * 4] = o4;
  }
}

// ----------------------------------------------------------------
extern "C" void kernel_launch(void* const* d_in, const int* in_sizes, int n_in,
                              void* d_out, int out_size, void* d_ws, size_t ws_size,
                              hipStream_t stream) {
  const float* x  = (const float*)d_in[0];
  const float* fc = (const float*)d_in[1];
  const float* fs = (const float*)d_in[2];
  const float* wq = (const float*)d_in[3];
  const float* wk = (const float*)d_in[4];
  const float* wv = (const float*)d_in[5];
  const float* wo = (const float*)d_in[6];

  unsigned short* ws   = (unsigned short*)d_ws;
  unsigned short* xb   = ws;                       //  8388608
  unsigned short* wqkv = xb + 8388608;             // 12582912
  unsigned short* wob  = wqkv + 12582912;          //  4194304
  unsigned short* Qb   = wob + 4194304;            //  8388608
  unsigned short* Kb   = Qb + 8388608;             //  8388608
  unsigned short* Vt   = Kb + 8388608;             //  8388608  [b,h,d,s]
  unsigned short* Ob   = Vt + 8388608;             //  8388608

  cast_pack<<<24576, 256, 0, stream>>>(x, wq, wk, wv, wo, xb, wqkv, wob);
  gemm256<0><<<768, 512, 0, stream>>>(xb, wqkv, nullptr, Qb, Kb, Vt, fc, fs, 2048);
  attn_k<<<dim3(32, 32), 256, 0, stream>>>(Qb, Kb, Vt, Ob);
  gemm256<1><<<256, 512, 0, stream>>>(Ob, wob, (float*)d_out, nullptr, nullptr, nullptr, fc, fs, 2048);
}